// Round 12
// baseline (332.432 us; speedup 1.0000x reference)
//
#include <hip/hip_runtime.h>
#include <hip/hip_bf16.h>

#define NBINS 32
#define HSTR 33                    // padded row stride (floats): bank = (i+j) mod 32, spreads
#define WHIST (NBINS * HSTR)       // 1056 floats = 4224 B per wave-private histogram
#define NTHREADS 256
#define NVOX 884736                // 96^3
#define BPB 1024                   // grid (1024,2) = 2048 blocks = 8/CU -> 32 waves/CU
#define VPB 864                    // voxels per block: 1024*864 = 884736 exactly
#define NSLOTS 16

#if defined(__HIP_PLATFORM_AMD__)
#define LDS_FADD(p, v) unsafeAtomicAdd((p), (v))   // ds_add_f32, no CAS loop
#else
#define LDS_FADD(p, v) atomicAdd((p), (v))
#endif

// Parzen 6-tap window — tap selection/zeroing/normalization IDENTICAL to the
// validated R4-R11 kernels, but weights stay f32 (no fp16 quantization).
__device__ __forceinline__ void compute_w6(float x, int& kb, float* w) {
    float tt = x * 31.0f;
    float kf = rintf(tt);
    int ki = (int)kf;
    float u = tt - kf;               // [-0.5, 0.5]
    kb = ki - 3 + (u > 0.0f ? 1 : 0);
    float s = 0.0f;
#pragma unroll
    for (int o = 0; o < 6; ++o) {
        int b = kb + o;
        float d = tt - (float)b;
        float e = __expf(-2.0f * d * d);
        e = ((unsigned)b < NBINS) ? e : 0.0f;
        w[o] = e;
        s += e;
    }
    float rinv = 1.0f / s;
#pragma unroll
    for (int o = 0; o < 6; ++o) w[o] *= rinv;
}

__device__ __forceinline__ void accum_voxel(float* __restrict__ H, float px, float tx) {
    int ka, kbv;
    float wa[6], wb[6];
    compute_w6(px, ka, wa);
    compute_w6(tx, kbv, wb);
    int joff[6];
#pragma unroll
    for (int ob = 0; ob < 6; ++ob)
        joff[ob] = min(max(kbv + ob, 0), NBINS - 1);   // OOB taps: wb==0, clamped addr harmless
#pragma unroll
    for (int oa = 0; oa < 6; ++oa) {
        int ia = min(max(ka + oa, 0), NBINS - 1);
        float wv = wa[oa];
        float* row = H + ia * HSTR;
#pragma unroll
        for (int ob = 0; ob < 6; ++ob)
            LDS_FADD(&row[joff[ob]], wv * wb[ob]);
    }
}

__global__ __launch_bounds__(NTHREADS, 8)
void mi_hist_kernel(const float* __restrict__ pred, const float* __restrict__ targ,
                    float* __restrict__ hist /* [NSLOTS][2][32][32] */) {
    __shared__ float h[4][WHIST];                 // wave-private histograms, 16896 B

    const int tid = threadIdx.x;
    const int bx = blockIdx.x;
    const int batch = blockIdx.y;
    const int wid = tid >> 6;
    const int lane = tid & 63;
    const float* p = pred + (size_t)batch * NVOX;
    const float* t = targ + (size_t)batch * NVOX;
    float* H = h[wid];

    // zero own wave's histogram (wave-private + in-order LDS -> no barrier needed)
    for (int i = lane; i < WHIST; i += 64) H[i] = 0.0f;

    const size_t base = (size_t)bx * VPB;

    // 864 voxels/block = 3 full rounds of 256 + 96 extra spread 24/wave (balanced)
#pragma unroll
    for (int r = 0; r < 3; ++r) {
        int idx = r * NTHREADS + tid;
        float px = p[base + idx];
        float tx = t[base + idx];
        accum_voxel(H, px, tx);
    }
    {
        int eidx = 3 * NTHREADS + wid * 24 + lane;
        if (lane < 24) {
            float px = p[base + eidx];
            float tx = t[base + eidx];
            accum_voxel(H, px, tx);
        }
    }

    __syncthreads();                              // all waves' histograms complete

    // block reduce 4 wave-hists -> global atomic into slot (same slotting as R7-R11)
    float* G = hist + ((size_t)(bx & (NSLOTS - 1)) * 2 + batch) * 1024;
    for (int idx = tid; idx < 1024; idx += NTHREADS) {
        int r = idx >> 5, c = idx & 31;
        int off = r * HSTR + c;
        float s = h[0][off] + h[1][off] + h[2][off] + h[3][off];
        atomicAdd(&G[idx], s);
    }
}

__global__ void mi_reduce_kernel(const float* __restrict__ hist, float* __restrict__ out) {
    __shared__ float s_pab[2 * NBINS * NBINS];
    __shared__ double s_pa[2][NBINS];
    __shared__ double s_pb[2][NBINS];
    __shared__ double s_red[1024];
    const int tid = threadIdx.x;
    const double invN = 1.0 / (double)NVOX;

    for (int g = tid; g < 512; g += 1024) {
        float4 s = make_float4(0.f, 0.f, 0.f, 0.f);
        for (int sl = 0; sl < NSLOTS; ++sl) {
            float4 v = ((const float4*)hist)[sl * 512 + g];
            s.x += v.x; s.y += v.y; s.z += v.z; s.w += v.w;
        }
        ((float4*)s_pab)[g] = s;
    }
    __syncthreads();

    if (tid < 64) {
        int b = tid >> 5, i = tid & 31;
        double s = 0.0;
        for (int j = 0; j < NBINS; ++j) s += (double)s_pab[(b * NBINS + i) * NBINS + j];
        s_pa[b][i] = s * invN;
    } else if (tid < 128) {
        int t2 = tid - 64;
        int b = t2 >> 5, j = t2 & 31;
        double s = 0.0;
        for (int i = 0; i < NBINS; ++i) s += (double)s_pab[(b * NBINS + i) * NBINS + j];
        s_pb[b][j] = s * invN;
    }
    __syncthreads();

    double acc = 0.0;
    for (int idx = tid; idx < 2 * NBINS * NBINS; idx += 1024) {
        int b = idx >> 10;
        int cell = idx & 1023;
        int i = cell >> 5, j = cell & 31;
        double pab = (double)s_pab[idx] * invN;
        double papb = s_pa[b][i] * s_pb[b][j];
        acc += pab * log((pab + 1e-7) / (papb + 1e-7) + 1e-7);
    }
    s_red[tid] = acc;
    __syncthreads();
    for (int s2 = 512; s2 > 0; s2 >>= 1) {
        if (tid < s2) s_red[tid] += s_red[tid + s2];
        __syncthreads();
    }
    if (tid == 0) out[0] = (float)(-0.5 * s_red[0]);
}

extern "C" void kernel_launch(void* const* d_in, const int* in_sizes, int n_in,
                              void* d_out, int out_size, void* d_ws, size_t ws_size,
                              hipStream_t stream) {
    const float* pred = (const float*)d_in[0];
    const float* targ = (const float*)d_in[1];
    float* hist = (float*)d_ws;
    float* out = (float*)d_out;

    hipMemsetAsync(hist, 0, NSLOTS * 2 * NBINS * NBINS * sizeof(float), stream);
    dim3 grid(BPB, 2);
    hipLaunchKernelGGL(mi_hist_kernel, grid, dim3(NTHREADS), 0, stream, pred, targ, hist);
    hipLaunchKernelGGL(mi_reduce_kernel, dim3(1), dim3(1024), 0, stream, hist, out);
}

// Round 13
// 30.083 us; speedup vs baseline: 11.0504x; 11.0504x over previous
//
#include <hip/hip_runtime.h>
#include <hip/hip_bf16.h>

#define NBINS 32
#define CHUNK 128           // voxels per chunk per block
#define NROWS 34            // rows 1..32 = bins 0..31; rows 0/33 = clamp garbage
#define STR 136             // halfs per row; 272B stride: every row 16B-aligned, even 8-dw/bank spread
#define TILE_HALVES (NROWS * STR)   // 4624 halfs = 9248 B per tile
#define NTHREADS 256
#define NVOX 884736         // 96^3 = 6912 * 128
#define BPB 768             // grid (768,2) = 1536 blocks = exactly 6/CU
#define NCHUNKS 9           // 768 * 9 = 6912 slabs -> perfectly uniform, no tail
#define NSLOTS 16

typedef __attribute__((ext_vector_type(8))) _Float16 half8;
typedef __attribute__((ext_vector_type(16))) float f32x16;
typedef __attribute__((ext_vector_type(4))) int i32x4;

// Parzen 6-tap window — BIT-IDENTICAL math to the validated R4-R11 kernels.
__device__ __forceinline__ void compute_w(float x, int& kb, _Float16* wq) {
    float tt = x * 31.0f;
    float kf = rintf(tt);
    int ki = (int)kf;
    float u = tt - kf;               // [-0.5, 0.5]
    kb = ki - 3 + (u > 0.0f ? 1 : 0);
    float w[6];
    float s = 0.0f;
#pragma unroll
    for (int o = 0; o < 6; ++o) {
        int b = kb + o;
        float d = tt - (float)b;
        float e = __expf(-2.0f * d * d);
        e = ((unsigned)b < NBINS) ? e : 0.0f;
        w[o] = e;
        s += e;
    }
    float rinv = 1.0f / s;
#pragma unroll
    for (int o = 0; o < 6; ++o) wq[o] = (_Float16)(w[o] * rinv);
}

// Unconditional clamped writes: OOB taps land in garbage rows 0/33 (never read).
__device__ __forceinline__ void zero6(_Float16* __restrict__ L, int col, int kb) {
#pragma unroll
    for (int o = 0; o < 6; ++o) {
        int r = min(max(kb + o, -1), 32) + 1;
        L[r * STR + col] = (_Float16)0.0f;
    }
}
__device__ __forceinline__ void scatter6(_Float16* __restrict__ L, int col, int kb,
                                         const _Float16* wq) {
#pragma unroll
    for (int o = 0; o < 6; ++o) {
        int r = min(max(kb + o, -1), 32) + 1;
        L[r * STR + col] = wq[o];
    }
}

__global__ __launch_bounds__(NTHREADS, 6)
void mi_hist_kernel(const float* __restrict__ pred, const float* __restrict__ targ,
                    float* __restrict__ hist /* [NSLOTS][2][32][32] */) {
    // SINGLE tile pair (A,B): 18496 B -> 6 blocks/CU (110 KB), 85-VGPR cap (no spill)
    __shared__ __attribute__((aligned(16))) _Float16 smem[2 * TILE_HALVES];
    _Float16* TA = smem;
    _Float16* TB = smem + TILE_HALVES;

    const int tid = threadIdx.x;
    const int bx = blockIdx.x;
    const int batch = blockIdx.y;
    const int col = tid & 127;
    const bool isB = tid >= 128;                 // 0-127: pred tile, 128-255: targ tile
    const float* src = (isB ? targ : pred) + (size_t)batch * NVOX;
    _Float16* T = isB ? TB : TA;

    const int wid = tid >> 6;
    const int lane = tid & 63;
    // mfma_f32_32x32x16_f16: row(col)=lane&31 (bin b -> row b+1), wave wid owns K [wid*32,+32)
    const int frag = (1 + (lane & 31)) * STR + wid * 32 + 8 * (lane >> 5);

    // preload ALL 9 chunk values -> no vmem in the main loop
    float xs[NCHUNKS];
#pragma unroll
    for (int c = 0; c < NCHUNKS; ++c)
        xs[c] = src[((size_t)(c * BPB + bx)) * CHUNK + col];

    // zero both tiles once (2*4624/8 = 1156 b128)
    {
        i32x4 z = {0, 0, 0, 0};
        i32x4* zp = (i32x4*)smem;
#pragma unroll
        for (int i = 0; i < 5; ++i) {
            int idx = i * NTHREADS + tid;
            if (idx < (2 * TILE_HALVES) / 8) zp[idx] = z;
        }
    }

    f32x16 acc;
#pragma unroll
    for (int r = 0; r < 16; ++r) acc[r] = 0.0f;

    int kb_old = 0;

#define DO_MFMA() { \
        _Pragma("unroll") \
        for (int kk = 0; kk < 2; ++kk) { \
            half8 af = *(const half8*)&TA[frag + kk * 16]; \
            half8 bf = *(const half8*)&TB[frag + kk * 16]; \
            acc = __builtin_amdgcn_mfma_f32_32x32x16_f16(af, bf, acc, 0, 0, 0); \
        } }

    // chunk 0 (no stale taps yet)
    {
        _Float16 wq[6]; int kb;
        compute_w(xs[0], kb, wq);
        __syncthreads();                 // prologue zero visible
        scatter6(T, col, kb, wq);
        kb_old = kb;
        __syncthreads();                 // scatter visible
        DO_MFMA();
    }
#pragma unroll
    for (int c = 1; c < NCHUNKS; ++c) {
        _Float16 wq[6]; int kb;
        compute_w(xs[c], kb, wq);        // VALU overlaps MFMA pipe + other blocks' LDS phases
        __syncthreads();                 // prev MFMA ds_reads drained (WAR safe)
        zero6(T, col, kb_old);           // stale taps from chunk c-1
        scatter6(T, col, kb, wq);
        kb_old = kb;
        __syncthreads();                 // scatter visible
        DO_MFMA();
    }
    __syncthreads();                     // last MFMA reads drained before smem reuse

    // block reduce: 4 waves hold K-split partials of the SAME 32x32.
    // C/D layout (32x32): col = lane&31, row = (reg&3) + 8*(reg>>2) + 4*(lane>>5)
    float* red = (float*)smem;           // 4 * 1024 floats = 16 KB (fits 18.5 KB)
    const int colc = lane & 31;
    const int rlo = 4 * (lane >> 5);
#pragma unroll
    for (int r = 0; r < 16; ++r) {
        int rowc = (r & 3) + 8 * (r >> 2) + rlo;
        red[wid * 1024 + rowc * 32 + colc] = acc[r];
    }
    __syncthreads();
    float* H = hist + ((size_t)(bx & (NSLOTS - 1)) * 2 + batch) * 1024;
    for (int idx = tid; idx < 1024; idx += NTHREADS) {
        float s = red[idx] + red[1024 + idx] + red[2048 + idx] + red[3072 + idx];
        atomicAdd(&H[idx], s);
    }
}

__global__ void mi_reduce_kernel(const float* __restrict__ hist, float* __restrict__ out) {
    __shared__ float s_pab[2 * NBINS * NBINS];
    __shared__ double s_pa[2][NBINS];
    __shared__ double s_pb[2][NBINS];
    __shared__ double s_red[1024];
    const int tid = threadIdx.x;
    const double invN = 1.0 / (double)NVOX;

    for (int g = tid; g < 512; g += 1024) {
        float4 s = make_float4(0.f, 0.f, 0.f, 0.f);
        for (int sl = 0; sl < NSLOTS; ++sl) {
            float4 v = ((const float4*)hist)[sl * 512 + g];
            s.x += v.x; s.y += v.y; s.z += v.z; s.w += v.w;
        }
        ((float4*)s_pab)[g] = s;
    }
    __syncthreads();

    if (tid < 64) {
        int b = tid >> 5, i = tid & 31;
        double s = 0.0;
        for (int j = 0; j < NBINS; ++j) s += (double)s_pab[(b * NBINS + i) * NBINS + j];
        s_pa[b][i] = s * invN;
    } else if (tid < 128) {
        int t2 = tid - 64;
        int b = t2 >> 5, j = t2 & 31;
        double s = 0.0;
        for (int i = 0; i < NBINS; ++i) s += (double)s_pab[(b * NBINS + i) * NBINS + j];
        s_pb[b][j] = s * invN;
    }
    __syncthreads();

    double acc = 0.0;
    for (int idx = tid; idx < 2 * NBINS * NBINS; idx += 1024) {
        int b = idx >> 10;
        int cell = idx & 1023;
        int i = cell >> 5, j = cell & 31;
        double pab = (double)s_pab[idx] * invN;
        double papb = s_pa[b][i] * s_pb[b][j];
        acc += pab * log((pab + 1e-7) / (papb + 1e-7) + 1e-7);
    }
    s_red[tid] = acc;
    __syncthreads();
    for (int s2 = 512; s2 > 0; s2 >>= 1) {
        if (tid < s2) s_red[tid] += s_red[tid + s2];
        __syncthreads();
    }
    if (tid == 0) out[0] = (float)(-0.5 * s_red[0]);
}

extern "C" void kernel_launch(void* const* d_in, const int* in_sizes, int n_in,
                              void* d_out, int out_size, void* d_ws, size_t ws_size,
                              hipStream_t stream) {
    const float* pred = (const float*)d_in[0];
    const float* targ = (const float*)d_in[1];
    float* hist = (float*)d_ws;
    float* out = (float*)d_out;

    hipMemsetAsync(hist, 0, NSLOTS * 2 * NBINS * NBINS * sizeof(float), stream);
    dim3 grid(BPB, 2);
    hipLaunchKernelGGL(mi_hist_kernel, grid, dim3(NTHREADS), 0, stream, pred, targ, hist);
    hipLaunchKernelGGL(mi_reduce_kernel, dim3(1), dim3(1024), 0, stream, hist, out);
}